// Round 1
// 1197.641 us; speedup vs baseline: 1.1399x; 1.1399x over previous
//
#include <hip/hip_runtime.h>
#include <hip/hip_bf16.h>
#include <math.h>

// ---------------------------------------------------------------------------
// GCN-VAE encoder, round 3: replace the fp32 FC GEMMs.
// rocprof showed k_gemm (fc2, 512x1024x128) at 204us with 0.74% occupancy:
// 16 workgroups on 256 CUs, latency-bound, uncoalesced A loads. The FC
// layers are tiny (268/134 MFLOP) and weights are L2-resident -- the only
// thing that matters is parallelism + coalescing, not reuse tiling.
// New: k_fc1 / k_fc2 = one block per output row (512 blocks each), weight
// rows read fully coalesced, input row staged in LDS, fp32 throughout
// (bit-compatible accuracy with previous version).
// ---------------------------------------------------------------------------

#define THREADS 256

typedef short s8v __attribute__((ext_vector_type(8)));   // 8 bf16 = 4 VGPR
typedef float f4v __attribute__((ext_vector_type(4)));   // MFMA accum

__device__ inline float bf_lo(unsigned int u) {
    union { unsigned int i; float f; } c; c.i = u << 16; return c.f;
}
__device__ inline float bf_hi(unsigned int u) {
    union { unsigned int i; float f; } c; c.i = u & 0xffff0000u; return c.f;
}
__device__ inline unsigned short f2bf(float f) {
    __hip_bfloat16 h = __float2bfloat16(f);
    return *reinterpret_cast<unsigned short*>(&h);
}
__device__ inline float bf2f(unsigned short u) {
    union { unsigned int i; float f; } c; c.i = ((unsigned int)u) << 16; return c.f;
}

// ------------------------- graph structure ---------------------------------

__global__ void k_count(const int* __restrict__ col, int* __restrict__ counts, int E) {
    int e = blockIdx.x * blockDim.x + threadIdx.x;
    if (e < E) atomicAdd(&counts[col[e]], 1);
}

__global__ void k_dinv(const int* __restrict__ counts, float* __restrict__ dinv, int N) {
    int i = blockIdx.x * blockDim.x + threadIdx.x;
    if (i < N) dinv[i] = rsqrtf((float)(counts[i] + 1));   // +1 self loop
}

__global__ __launch_bounds__(1024) void k_scan(const int* __restrict__ counts,
                                               int* __restrict__ offsets, int N) {
    __shared__ int ssum[1024];
    int tid = threadIdx.x;
    int chunk = (N + 1023) / 1024;
    int begin = tid * chunk;
    int end = begin + chunk; if (end > N) end = N;
    int s = 0;
    for (int i = begin; i < end; ++i) s += counts[i] + 1;
    ssum[tid] = s;
    __syncthreads();
    for (int off = 1; off < 1024; off <<= 1) {
        int v = 0;
        if (tid >= off) v = ssum[tid - off];
        __syncthreads();
        if (tid >= off) ssum[tid] += v;
        __syncthreads();
    }
    int prefix = (tid == 0) ? 0 : ssum[tid - 1];
    for (int i = begin; i < end; ++i) {
        offsets[i] = prefix;
        prefix += counts[i] + 1;
    }
    if (end == N && begin < N) offsets[N] = prefix;
}

__global__ void k_init_cursor(const int* __restrict__ offsets, int* __restrict__ cursor, int N) {
    int i = blockIdx.x * blockDim.x + threadIdx.x;
    if (i < N) cursor[i] = offsets[i];
}

__global__ void k_scatter(const int* __restrict__ row, const int* __restrict__ col,
                          const float* __restrict__ dinv, int* __restrict__ cursor,
                          int* __restrict__ csr_row, float* __restrict__ csr_norm,
                          int E, int N) {
    int e = blockIdx.x * blockDim.x + threadIdx.x;
    if (e < E) {
        int r = row[e], c = col[e];
        int slot = atomicAdd(&cursor[c], 1);
        csr_row[slot] = r;
        csr_norm[slot] = dinv[r] * dinv[c];
    } else if (e < E + N) {
        int i = e - E;
        int slot = atomicAdd(&cursor[i], 1);
        csr_row[slot] = i;
        float d = dinv[i];
        csr_norm[slot] = d * d;
    }
}

// ------------------------- casts / weight prep -----------------------------

__global__ void k_cast_bf16(const float* __restrict__ src, unsigned short* __restrict__ dst, int n) {
    int i = blockIdx.x * blockDim.x + threadIdx.x;
    if (i < n) dst[i] = f2bf(src[i]);
}

// W [K,Nc] fp32 -> WT [Nc,K] bf16
__global__ void k_prep_w(const float* __restrict__ W, unsigned short* __restrict__ WT,
                         int K, int Nc) {
    int id = blockIdx.x * blockDim.x + threadIdx.x;
    if (id < K * Nc) {
        int k = id / Nc, n = id % Nc;
        WT[(size_t)n * K + k] = f2bf(W[id]);
    }
}

// ------------------------- aggregation (gather, bf16 in/out) ---------------
// block: (F/8, nodes_per_block). Each thread owns 8 channels of one node.
__global__ void k_agg(const unsigned short* __restrict__ h,
                      const int* __restrict__ offsets,
                      const int* __restrict__ csr_row,
                      const float* __restrict__ csr_nrm,
                      unsigned short* __restrict__ g, int N, int F) {
    int node = blockIdx.x * blockDim.y + threadIdx.y;
    if (node >= N) return;
    int c8 = threadIdx.x * 8;
    int off0 = offsets[node], off1 = offsets[node + 1];
    float a0=0.f,a1=0.f,a2=0.f,a3=0.f,a4=0.f,a5=0.f,a6=0.f,a7=0.f;
    for (int sl = off0; sl < off1; ++sl) {
        int r = csr_row[sl];
        float w = csr_nrm[sl];
        uint4 v = *(const uint4*)(h + (size_t)r * F + c8);
        a0 += w * bf_lo(v.x); a1 += w * bf_hi(v.x);
        a2 += w * bf_lo(v.y); a3 += w * bf_hi(v.y);
        a4 += w * bf_lo(v.z); a5 += w * bf_hi(v.z);
        a6 += w * bf_lo(v.w); a7 += w * bf_hi(v.w);
    }
    uint4 o;
    o.x = (unsigned)f2bf(a0) | ((unsigned)f2bf(a1) << 16);
    o.y = (unsigned)f2bf(a2) | ((unsigned)f2bf(a3) << 16);
    o.z = (unsigned)f2bf(a4) | ((unsigned)f2bf(a5) << 16);
    o.w = (unsigned)f2bf(a6) | ((unsigned)f2bf(a7) << 16);
    *(uint4*)(g + (size_t)node * F + c8) = o;
}

// ------------------------- bf16 MFMA GEMM ----------------------------------
// C[M,Nc] = A[M,K](bf16) @ W (given as WT[Nc,K] bf16), +bias, opt relu.
// Out fp32 or bf16. BM=128, BN=64, BK=64, 256 threads (4 waves).
#define GBM 128
#define GBN 64
#define GBK 64
#define LDP 72   // padded LDS row stride (shorts)

__global__ __launch_bounds__(256) void k_gemm_mfma(
    const unsigned short* __restrict__ A,
    const unsigned short* __restrict__ WT,
    const float* __restrict__ bias,
    void* __restrict__ Cout, int M, int K, int Nc,
    int dorelu, int out_bf16) {
    __shared__ unsigned short sA[GBM * LDP];
    __shared__ unsigned short sB[GBN * LDP];
    const int tid = threadIdx.x;
    const int wave = tid >> 6;
    const int lane = tid & 63;
    const int bm = blockIdx.x * GBM;
    const int bn = blockIdx.y * GBN;

    f4v acc[2][4];
    #pragma unroll
    for (int i = 0; i < 2; ++i)
        #pragma unroll
        for (int j = 0; j < 4; ++j) acc[i][j] = (f4v){0.f, 0.f, 0.f, 0.f};

    const int lrow = tid >> 3;          // 0..31
    const int lk = (tid & 7) * 8;       // 0,8,...,56
    const int fr = lane & 15;
    const int fk = (lane >> 4) * 8;

    for (int k0 = 0; k0 < K; k0 += GBK) {
        #pragma unroll
        for (int p = 0; p < 4; ++p) {
            int r = lrow + p * 32;
            int gm = bm + r;
            uint4 v = make_uint4(0u, 0u, 0u, 0u);
            if (gm < M) v = *(const uint4*)(A + (size_t)gm * K + k0 + lk);
            *(uint4*)(&sA[r * LDP + lk]) = v;
        }
        #pragma unroll
        for (int p = 0; p < 2; ++p) {
            int n = lrow + p * 32;
            uint4 v = *(const uint4*)(WT + (size_t)(bn + n) * K + k0 + lk);
            *(uint4*)(&sB[n * LDP + lk]) = v;
        }
        __syncthreads();
        #pragma unroll
        for (int ks = 0; ks < 2; ++ks) {
            s8v a0 = *(const s8v*)(&sA[(wave * 32 + fr) * LDP + ks * 32 + fk]);
            s8v a1 = *(const s8v*)(&sA[(wave * 32 + 16 + fr) * LDP + ks * 32 + fk]);
            #pragma unroll
            for (int nt = 0; nt < 4; ++nt) {
                s8v b = *(const s8v*)(&sB[(nt * 16 + fr) * LDP + ks * 32 + fk]);
                acc[0][nt] = __builtin_amdgcn_mfma_f32_16x16x32_bf16(a0, b, acc[0][nt], 0, 0, 0);
                acc[1][nt] = __builtin_amdgcn_mfma_f32_16x16x32_bf16(a1, b, acc[1][nt], 0, 0, 0);
            }
        }
        __syncthreads();
    }

    const int col_l = lane & 15;
    const int row_q = (lane >> 4) * 4;
    #pragma unroll
    for (int mt = 0; mt < 2; ++mt) {
        #pragma unroll
        for (int nt = 0; nt < 4; ++nt) {
            #pragma unroll
            for (int i = 0; i < 4; ++i) {
                int row = bm + wave * 32 + mt * 16 + row_q + i;
                int col = bn + nt * 16 + col_l;
                if (row < M) {
                    float v = acc[mt][nt][i] + bias[col];
                    if (dorelu) v = fmaxf(v, 0.f);
                    if (out_bf16)
                        ((unsigned short*)Cout)[(size_t)row * Nc + col] = f2bf(v);
                    else
                        ((float*)Cout)[(size_t)row * Nc + col] = v;
                }
            }
        }
    }
}

// ------------------------- FC layers (fp32, latency-optimized) -------------
// fc1: hid[m, 0..1023] = relu(x2[m, 0..255] @ W + b).
// One block per output row m (512 blocks). x2 row staged in LDS; each thread
// owns 4 contiguous cols -> float4 W loads fully coalesced across the block.
// W (1 MB) is L2-resident; aggregate W traffic 512 MB from L2 ~= 15 us.
__global__ __launch_bounds__(256) void k_fc1(const float* __restrict__ x2,
                                             const float* __restrict__ W,
                                             const float* __restrict__ bias,
                                             float* __restrict__ hid,
                                             int K, int Nc) {
    const int m = blockIdx.x;
    const int t = threadIdx.x;
    __shared__ float sx[256];
    for (int k = t; k < K; k += 256) sx[k] = x2[(size_t)m * K + k];
    __syncthreads();
    const int nc4 = Nc >> 2;
    const float4* Wv = (const float4*)W;
    float4 acc = make_float4(0.f, 0.f, 0.f, 0.f);
    #pragma unroll 4
    for (int k = 0; k < K; ++k) {
        float a = sx[k];                       // LDS broadcast (free)
        float4 w = Wv[(size_t)k * nc4 + t];    // coalesced 16B/lane
        acc.x += a * w.x; acc.y += a * w.y;
        acc.z += a * w.z; acc.w += a * w.w;
    }
    float4 b = ((const float4*)bias)[t];
    float4 r;
    r.x = fmaxf(acc.x + b.x, 0.f);
    r.y = fmaxf(acc.y + b.y, 0.f);
    r.z = fmaxf(acc.z + b.z, 0.f);
    r.w = fmaxf(acc.w + b.w, 0.f);
    ((float4*)hid)[(size_t)m * nc4 + t] = r;
}

// fc2: pmvo[m, 0..127] = hid[m, 0..1023] @ W + b. One block (128 thr) per
// row; hid row in LDS; one col per thread, k unrolled x4 for 4 independent
// FMA chains. W (0.5 MB) L2-resident; 256 MB aggregate ~= 8 us.
__global__ __launch_bounds__(128) void k_fc2(const float* __restrict__ hid,
                                             const float* __restrict__ W,
                                             const float* __restrict__ bias,
                                             float* __restrict__ out,
                                             int K, int Nc) {
    const int m = blockIdx.x;
    const int c = threadIdx.x;
    __shared__ float sh[1024];
    for (int k = c; k < K; k += 128) sh[k] = hid[(size_t)m * K + k];
    __syncthreads();
    float a0 = 0.f, a1 = 0.f, a2 = 0.f, a3 = 0.f;
    for (int k = 0; k < K; k += 4) {
        a0 += sh[k    ] * W[(size_t)(k    ) * Nc + c];
        a1 += sh[k + 1] * W[(size_t)(k + 1) * Nc + c];
        a2 += sh[k + 2] * W[(size_t)(k + 2) * Nc + c];
        a3 += sh[k + 3] * W[(size_t)(k + 3) * Nc + c];
    }
    out[(size_t)m * Nc + c] = (a0 + a1) + (a2 + a3) + bias[c];
}

// ------------------------- misc --------------------------------------------

__global__ void k_amvo(const float* __restrict__ mu, const float* __restrict__ lv,
                       const float* __restrict__ eps, float* __restrict__ out, size_t n) {
    size_t i = (size_t)blockIdx.x * blockDim.x + threadIdx.x;
    if (i < n) out[i] = mu[i] + eps[i] * expf(0.5f * lv[i]);
}

__global__ void k_gstart(const int* __restrict__ batch, int* __restrict__ gstart, int Nn, int B) {
    int b = blockIdx.x * blockDim.x + threadIdx.x;
    if (b > B) return;
    int lo = 0, hi = Nn;
    while (lo < hi) {
        int mid = (lo + hi) >> 1;
        if (batch[mid] < b) lo = mid + 1; else hi = mid;
    }
    gstart[b] = lo;
}

// max-pool over bf16 h3 -> fp32 x2
__global__ void k_pool_max(const unsigned short* __restrict__ h, const int* __restrict__ gstart,
                           float* __restrict__ x2, int F) {
    int b = blockIdx.x;
    int s = gstart[b], e = gstart[b + 1];
    for (int c = threadIdx.x; c < F; c += blockDim.x) {
        float mv = -INFINITY;
        for (int i = s; i < e; ++i) mv = fmaxf(mv, bf2f(h[(size_t)i * F + c]));
        x2[(size_t)b * F + c] = mv;
    }
}

static inline int ceil_div(int a, int b) { return (a + b - 1) / b; }

extern "C" void kernel_launch(void* const* d_in, const int* in_sizes, int n_in,
                              void* d_out, int out_size, void* d_ws, size_t ws_size,
                              hipStream_t stream) {
    const int F0 = 64;
    const int N = in_sizes[0] / F0;            // 100000
    const int E = in_sizes[1] / 2;             // 400000
    const int F4 = 4 * F0;                     // 256
    const int B = (out_size - 3 * N * F4) / 128;  // 512
    const int M = E + N;

    const float* x     = (const float*)d_in[0];
    const int*   ei    = (const int*)d_in[1];
    const int*   batch = (const int*)d_in[2];
    const float* eps   = (const float*)d_in[3];
    const float* W1  = (const float*)d_in[4];  const float* b1  = (const float*)d_in[5];
    const float* W2  = (const float*)d_in[6];  const float* b2  = (const float*)d_in[7];
    const float* W3  = (const float*)d_in[8];  const float* b3  = (const float*)d_in[9];
    const float* Wmu = (const float*)d_in[10]; const float* bmu = (const float*)d_in[11];
    const float* Wlv = (const float*)d_in[12]; const float* blv = (const float*)d_in[13];
    const float* fc1w = (const float*)d_in[14]; const float* fc1b = (const float*)d_in[15];
    const float* fc2w = (const float*)d_in[16]; const float* fc2b = (const float*)d_in[17];

    const int* e_row = ei;
    const int* e_col = ei + E;

    float* out  = (float*)d_out;
    float* amvo = out;
    float* mu   = out + (size_t)N * F4;
    float* lv   = out + 2 * (size_t)N * F4;
    float* pmvo = out + 3 * (size_t)N * F4;

    // --- workspace carve ---
    char* w = (char*)d_ws;
    auto alloc = [&](size_t bytes) -> void* {
        void* p = (void*)w;
        w += (bytes + 255) & ~(size_t)255;
        return p;
    };
    float* dinv    = (float*)alloc((size_t)N * 4);
    int*   counts  = (int*)alloc((size_t)N * 4);
    int*   offsets = (int*)alloc((size_t)(N + 1) * 4);
    int*   csr_row = (int*)alloc((size_t)M * 4);
    float* csr_nrm = (float*)alloc((size_t)M * 4);
    int*   gstart  = (int*)alloc((size_t)(B + 1) * 4);
    unsigned short* xb  = (unsigned short*)alloc((size_t)N * F0 * 2);
    unsigned short* h1  = (unsigned short*)alloc((size_t)N * 128 * 2);
    unsigned short* h2  = (unsigned short*)alloc((size_t)N * 192 * 2);
    unsigned short* h3  = (unsigned short*)alloc((size_t)N * 256 * 2);
    unsigned short* g   = (unsigned short*)alloc((size_t)N * 256 * 2);  // reused g1..g4
    unsigned short* wt1 = (unsigned short*)alloc((size_t)64 * 128 * 2);
    unsigned short* wt2 = (unsigned short*)alloc((size_t)128 * 192 * 2);
    unsigned short* wt3 = (unsigned short*)alloc((size_t)192 * 256 * 2);
    unsigned short* wtm = (unsigned short*)alloc((size_t)256 * 256 * 2);
    unsigned short* wtl = (unsigned short*)alloc((size_t)256 * 256 * 2);
    float* x2  = (float*)alloc((size_t)B * F4 * 4);
    float* hid = (float*)alloc((size_t)B * 1024 * 4);
    (void)ws_size; (void)n_in;

    // --- 1. graph structure ---
    hipMemsetAsync(counts, 0, (size_t)N * 4, stream);
    k_count<<<ceil_div(E, THREADS), THREADS, 0, stream>>>(e_col, counts, E);
    k_dinv<<<ceil_div(N, THREADS), THREADS, 0, stream>>>(counts, dinv, N);
    k_scan<<<1, 1024, 0, stream>>>(counts, offsets, N);
    k_init_cursor<<<ceil_div(N, THREADS), THREADS, 0, stream>>>(offsets, counts, N);
    k_scatter<<<ceil_div(E + N, THREADS), THREADS, 0, stream>>>(
        e_row, e_col, dinv, counts, csr_row, csr_nrm, E, N);

    // --- 2. casts + weight prep ---
    k_cast_bf16<<<ceil_div(N * F0, THREADS), THREADS, 0, stream>>>(x, xb, N * F0);
    k_prep_w<<<ceil_div(64 * 128, THREADS), THREADS, 0, stream>>>(W1, wt1, 64, 128);
    k_prep_w<<<ceil_div(128 * 192, THREADS), THREADS, 0, stream>>>(W2, wt2, 128, 192);
    k_prep_w<<<ceil_div(192 * 256, THREADS), THREADS, 0, stream>>>(W3, wt3, 192, 256);
    k_prep_w<<<ceil_div(256 * 256, THREADS), THREADS, 0, stream>>>(Wmu, wtm, 256, 256);
    k_prep_w<<<ceil_div(256 * 256, THREADS), THREADS, 0, stream>>>(Wlv, wtl, 256, 256);

    // --- 3. GCN stack: agg -> transform ---
    // g1 = agg(xb) [N,64]; h1 = relu(g1@W1+b1) [N,128]
    {
        dim3 blk(8, 32); // 64ch
        k_agg<<<ceil_div(N, 32), blk, 0, stream>>>(xb, offsets, csr_row, csr_nrm, g, N, 64);
        dim3 gg(ceil_div(N, GBM), 128 / GBN);
        k_gemm_mfma<<<gg, 256, 0, stream>>>(g, wt1, b1, h1, N, 64, 128, 1, 1);
    }
    // g2 = agg(h1) [N,128]; h2 = relu(g2@W2+b2) [N,192]
    {
        dim3 blk(16, 16);
        k_agg<<<ceil_div(N, 16), blk, 0, stream>>>(h1, offsets, csr_row, csr_nrm, g, N, 128);
        dim3 gg(ceil_div(N, GBM), 192 / GBN);
        k_gemm_mfma<<<gg, 256, 0, stream>>>(g, wt2, b2, h2, N, 128, 192, 1, 1);
    }
    // g3 = agg(h2) [N,192]; h3 = relu(g3@W3+b3) [N,256]
    {
        dim3 blk(24, 8);
        k_agg<<<ceil_div(N, 8), blk, 0, stream>>>(h2, offsets, csr_row, csr_nrm, g, N, 192);
        dim3 gg(ceil_div(N, GBM), 256 / GBN);
        k_gemm_mfma<<<gg, 256, 0, stream>>>(g, wt3, b3, h3, N, 192, 256, 1, 1);
    }
    // g4 = agg(h3) [N,256]; mu = g4@Wmu+bmu; lv = g4@Wlv+blv (fp32 out)
    {
        dim3 blk(32, 8);
        k_agg<<<ceil_div(N, 8), blk, 0, stream>>>(h3, offsets, csr_row, csr_nrm, g, N, 256);
        dim3 gg(ceil_div(N, GBM), 256 / GBN);
        k_gemm_mfma<<<gg, 256, 0, stream>>>(g, wtm, bmu, mu, N, 256, 256, 0, 0);
        k_gemm_mfma<<<gg, 256, 0, stream>>>(g, wtl, blv, lv, N, 256, 256, 0, 0);
    }

    // --- 4. reparameterize ---
    {
        size_t n = (size_t)N * F4;
        k_amvo<<<(int)((n + THREADS - 1) / THREADS), THREADS, 0, stream>>>(mu, lv, eps, amvo, n);
    }

    // --- 5. pool + MLP (fp32, one block per row: 512-block grids) ---
    k_gstart<<<ceil_div(B + 1, THREADS), THREADS, 0, stream>>>(batch, gstart, N, B);
    k_pool_max<<<B, 256, 0, stream>>>(h3, gstart, x2, F4);
    k_fc1<<<B, 256, 0, stream>>>(x2, fc1w, fc1b, hid, F4, 1024);
    k_fc2<<<B, 128, 0, stream>>>(hid, fc2w, fc2b, pmvo, 1024, 128);
}

// Round 2
// 1153.491 us; speedup vs baseline: 1.1836x; 1.0383x over previous
//
#include <hip/hip_runtime.h>
#include <hip/hip_bf16.h>
#include <math.h>

// ---------------------------------------------------------------------------
// GCN-VAE encoder, round 4.
// r3 rocprof: harness poison-fills dominate the capture (1.2GB WRITE each,
// not ours). Our pipeline is spread thin; the remaining structural waste:
//   - mu/lv GEMMs read the same A (g4, 51MB) twice, then k_amvo re-reads
//     mu+lv (205MB fp32) from HBM just to combine with eps.
//     -> k_gemm_mfma_dual: one pass computes BOTH mu and lv tiles and the
//        amvo epilogue in-register. Saves ~256MB HBM + 2 launches.
//        Bit-identical: same MFMA order, amvo from the same fp32 values.
//   - k_pool_max was 512 serial blocks -> re-gridded (B x 4) x (64ch x 4row)
//     with LDS tree reduce: 4x parallelism, coalesced 128B wave reads.
// ---------------------------------------------------------------------------

#define THREADS 256

typedef short s8v __attribute__((ext_vector_type(8)));   // 8 bf16 = 4 VGPR
typedef float f4v __attribute__((ext_vector_type(4)));   // MFMA accum

__device__ inline float bf_lo(unsigned int u) {
    union { unsigned int i; float f; } c; c.i = u << 16; return c.f;
}
__device__ inline float bf_hi(unsigned int u) {
    union { unsigned int i; float f; } c; c.i = u & 0xffff0000u; return c.f;
}
__device__ inline unsigned short f2bf(float f) {
    __hip_bfloat16 h = __float2bfloat16(f);
    return *reinterpret_cast<unsigned short*>(&h);
}
__device__ inline float bf2f(unsigned short u) {
    union { unsigned int i; float f; } c; c.i = ((unsigned int)u) << 16; return c.f;
}

// ------------------------- graph structure ---------------------------------

__global__ void k_count(const int* __restrict__ col, int* __restrict__ counts, int E) {
    int e = blockIdx.x * blockDim.x + threadIdx.x;
    if (e < E) atomicAdd(&counts[col[e]], 1);
}

__global__ void k_dinv(const int* __restrict__ counts, float* __restrict__ dinv, int N) {
    int i = blockIdx.x * blockDim.x + threadIdx.x;
    if (i < N) dinv[i] = rsqrtf((float)(counts[i] + 1));   // +1 self loop
}

__global__ __launch_bounds__(1024) void k_scan(const int* __restrict__ counts,
                                               int* __restrict__ offsets, int N) {
    __shared__ int ssum[1024];
    int tid = threadIdx.x;
    int chunk = (N + 1023) / 1024;
    int begin = tid * chunk;
    int end = begin + chunk; if (end > N) end = N;
    int s = 0;
    for (int i = begin; i < end; ++i) s += counts[i] + 1;
    ssum[tid] = s;
    __syncthreads();
    for (int off = 1; off < 1024; off <<= 1) {
        int v = 0;
        if (tid >= off) v = ssum[tid - off];
        __syncthreads();
        if (tid >= off) ssum[tid] += v;
        __syncthreads();
    }
    int prefix = (tid == 0) ? 0 : ssum[tid - 1];
    for (int i = begin; i < end; ++i) {
        offsets[i] = prefix;
        prefix += counts[i] + 1;
    }
    if (end == N && begin < N) offsets[N] = prefix;
}

__global__ void k_init_cursor(const int* __restrict__ offsets, int* __restrict__ cursor, int N) {
    int i = blockIdx.x * blockDim.x + threadIdx.x;
    if (i < N) cursor[i] = offsets[i];
}

__global__ void k_scatter(const int* __restrict__ row, const int* __restrict__ col,
                          const float* __restrict__ dinv, int* __restrict__ cursor,
                          int* __restrict__ csr_row, float* __restrict__ csr_norm,
                          int E, int N) {
    int e = blockIdx.x * blockDim.x + threadIdx.x;
    if (e < E) {
        int r = row[e], c = col[e];
        int slot = atomicAdd(&cursor[c], 1);
        csr_row[slot] = r;
        csr_norm[slot] = dinv[r] * dinv[c];
    } else if (e < E + N) {
        int i = e - E;
        int slot = atomicAdd(&cursor[i], 1);
        csr_row[slot] = i;
        float d = dinv[i];
        csr_norm[slot] = d * d;
    }
}

// ------------------------- casts / weight prep -----------------------------

__global__ void k_cast_bf16(const float* __restrict__ src, unsigned short* __restrict__ dst, int n) {
    int i = blockIdx.x * blockDim.x + threadIdx.x;
    if (i < n) dst[i] = f2bf(src[i]);
}

// W [K,Nc] fp32 -> WT [Nc,K] bf16
__global__ void k_prep_w(const float* __restrict__ W, unsigned short* __restrict__ WT,
                         int K, int Nc) {
    int id = blockIdx.x * blockDim.x + threadIdx.x;
    if (id < K * Nc) {
        int k = id / Nc, n = id % Nc;
        WT[(size_t)n * K + k] = f2bf(W[id]);
    }
}

// ------------------------- aggregation (gather, bf16 in/out) ---------------
// block: (F/8, nodes_per_block). Each thread owns 8 channels of one node.
__global__ void k_agg(const unsigned short* __restrict__ h,
                      const int* __restrict__ offsets,
                      const int* __restrict__ csr_row,
                      const float* __restrict__ csr_nrm,
                      unsigned short* __restrict__ g, int N, int F) {
    int node = blockIdx.x * blockDim.y + threadIdx.y;
    if (node >= N) return;
    int c8 = threadIdx.x * 8;
    int off0 = offsets[node], off1 = offsets[node + 1];
    float a0=0.f,a1=0.f,a2=0.f,a3=0.f,a4=0.f,a5=0.f,a6=0.f,a7=0.f;
    for (int sl = off0; sl < off1; ++sl) {
        int r = csr_row[sl];
        float w = csr_nrm[sl];
        uint4 v = *(const uint4*)(h + (size_t)r * F + c8);
        a0 += w * bf_lo(v.x); a1 += w * bf_hi(v.x);
        a2 += w * bf_lo(v.y); a3 += w * bf_hi(v.y);
        a4 += w * bf_lo(v.z); a5 += w * bf_hi(v.z);
        a6 += w * bf_lo(v.w); a7 += w * bf_hi(v.w);
    }
    uint4 o;
    o.x = (unsigned)f2bf(a0) | ((unsigned)f2bf(a1) << 16);
    o.y = (unsigned)f2bf(a2) | ((unsigned)f2bf(a3) << 16);
    o.z = (unsigned)f2bf(a4) | ((unsigned)f2bf(a5) << 16);
    o.w = (unsigned)f2bf(a6) | ((unsigned)f2bf(a7) << 16);
    *(uint4*)(g + (size_t)node * F + c8) = o;
}

// ------------------------- bf16 MFMA GEMM ----------------------------------
// C[M,Nc] = A[M,K](bf16) @ W (given as WT[Nc,K] bf16), +bias, opt relu.
// Out fp32 or bf16. BM=128, BN=64, BK=64, 256 threads (4 waves).
#define GBM 128
#define GBN 64
#define GBK 64
#define LDP 72   // padded LDS row stride (shorts)

__global__ __launch_bounds__(256) void k_gemm_mfma(
    const unsigned short* __restrict__ A,
    const unsigned short* __restrict__ WT,
    const float* __restrict__ bias,
    void* __restrict__ Cout, int M, int K, int Nc,
    int dorelu, int out_bf16) {
    __shared__ unsigned short sA[GBM * LDP];
    __shared__ unsigned short sB[GBN * LDP];
    const int tid = threadIdx.x;
    const int wave = tid >> 6;
    const int lane = tid & 63;
    const int bm = blockIdx.x * GBM;
    const int bn = blockIdx.y * GBN;

    f4v acc[2][4];
    #pragma unroll
    for (int i = 0; i < 2; ++i)
        #pragma unroll
        for (int j = 0; j < 4; ++j) acc[i][j] = (f4v){0.f, 0.f, 0.f, 0.f};

    const int lrow = tid >> 3;          // 0..31
    const int lk = (tid & 7) * 8;       // 0,8,...,56
    const int fr = lane & 15;
    const int fk = (lane >> 4) * 8;

    for (int k0 = 0; k0 < K; k0 += GBK) {
        #pragma unroll
        for (int p = 0; p < 4; ++p) {
            int r = lrow + p * 32;
            int gm = bm + r;
            uint4 v = make_uint4(0u, 0u, 0u, 0u);
            if (gm < M) v = *(const uint4*)(A + (size_t)gm * K + k0 + lk);
            *(uint4*)(&sA[r * LDP + lk]) = v;
        }
        #pragma unroll
        for (int p = 0; p < 2; ++p) {
            int n = lrow + p * 32;
            uint4 v = *(const uint4*)(WT + (size_t)(bn + n) * K + k0 + lk);
            *(uint4*)(&sB[n * LDP + lk]) = v;
        }
        __syncthreads();
        #pragma unroll
        for (int ks = 0; ks < 2; ++ks) {
            s8v a0 = *(const s8v*)(&sA[(wave * 32 + fr) * LDP + ks * 32 + fk]);
            s8v a1 = *(const s8v*)(&sA[(wave * 32 + 16 + fr) * LDP + ks * 32 + fk]);
            #pragma unroll
            for (int nt = 0; nt < 4; ++nt) {
                s8v b = *(const s8v*)(&sB[(nt * 16 + fr) * LDP + ks * 32 + fk]);
                acc[0][nt] = __builtin_amdgcn_mfma_f32_16x16x32_bf16(a0, b, acc[0][nt], 0, 0, 0);
                acc[1][nt] = __builtin_amdgcn_mfma_f32_16x16x32_bf16(a1, b, acc[1][nt], 0, 0, 0);
            }
        }
        __syncthreads();
    }

    const int col_l = lane & 15;
    const int row_q = (lane >> 4) * 4;
    #pragma unroll
    for (int mt = 0; mt < 2; ++mt) {
        #pragma unroll
        for (int nt = 0; nt < 4; ++nt) {
            #pragma unroll
            for (int i = 0; i < 4; ++i) {
                int row = bm + wave * 32 + mt * 16 + row_q + i;
                int col = bn + nt * 16 + col_l;
                if (row < M) {
                    float v = acc[mt][nt][i] + bias[col];
                    if (dorelu) v = fmaxf(v, 0.f);
                    if (out_bf16)
                        ((unsigned short*)Cout)[(size_t)row * Nc + col] = f2bf(v);
                    else
                        ((float*)Cout)[(size_t)row * Nc + col] = v;
                }
            }
        }
    }
}

// ------------------------- dual bf16 MFMA GEMM + reparam epilogue ----------
// One pass over A computes mu = A@Wm + bmu and lv = A@Wl + blv for the same
// output tile, then amvo = mu + eps*exp(0.5*lv) in-register. Saves re-reading
// A for the second GEMM and re-reading mu/lv (205MB fp32) in a separate
// elementwise kernel. MFMA order identical to the split version.
__global__ __launch_bounds__(256) void k_gemm_mfma_dual(
    const unsigned short* __restrict__ A,
    const unsigned short* __restrict__ WTm,
    const unsigned short* __restrict__ WTl,
    const float* __restrict__ bmu,
    const float* __restrict__ blv,
    const float* __restrict__ eps,
    float* __restrict__ mu,
    float* __restrict__ lv,
    float* __restrict__ amvo,
    int M, int K, int Nc) {
    __shared__ unsigned short sA[GBM * LDP];
    __shared__ unsigned short sBm[GBN * LDP];
    __shared__ unsigned short sBl[GBN * LDP];
    const int tid = threadIdx.x;
    const int wave = tid >> 6;
    const int lane = tid & 63;
    const int bm = blockIdx.x * GBM;
    const int bn = blockIdx.y * GBN;

    f4v accM[2][4], accL[2][4];
    #pragma unroll
    for (int i = 0; i < 2; ++i)
        #pragma unroll
        for (int j = 0; j < 4; ++j) {
            accM[i][j] = (f4v){0.f, 0.f, 0.f, 0.f};
            accL[i][j] = (f4v){0.f, 0.f, 0.f, 0.f};
        }

    const int lrow = tid >> 3;          // 0..31
    const int lk = (tid & 7) * 8;       // 0,8,...,56
    const int fr = lane & 15;
    const int fk = (lane >> 4) * 8;

    for (int k0 = 0; k0 < K; k0 += GBK) {
        #pragma unroll
        for (int p = 0; p < 4; ++p) {
            int r = lrow + p * 32;
            int gm = bm + r;
            uint4 v = make_uint4(0u, 0u, 0u, 0u);
            if (gm < M) v = *(const uint4*)(A + (size_t)gm * K + k0 + lk);
            *(uint4*)(&sA[r * LDP + lk]) = v;
        }
        #pragma unroll
        for (int p = 0; p < 2; ++p) {
            int n = lrow + p * 32;
            uint4 vm = *(const uint4*)(WTm + (size_t)(bn + n) * K + k0 + lk);
            uint4 vl = *(const uint4*)(WTl + (size_t)(bn + n) * K + k0 + lk);
            *(uint4*)(&sBm[n * LDP + lk]) = vm;
            *(uint4*)(&sBl[n * LDP + lk]) = vl;
        }
        __syncthreads();
        #pragma unroll
        for (int ks = 0; ks < 2; ++ks) {
            s8v a0 = *(const s8v*)(&sA[(wave * 32 + fr) * LDP + ks * 32 + fk]);
            s8v a1 = *(const s8v*)(&sA[(wave * 32 + 16 + fr) * LDP + ks * 32 + fk]);
            #pragma unroll
            for (int nt = 0; nt < 4; ++nt) {
                s8v bm_ = *(const s8v*)(&sBm[(nt * 16 + fr) * LDP + ks * 32 + fk]);
                s8v bl_ = *(const s8v*)(&sBl[(nt * 16 + fr) * LDP + ks * 32 + fk]);
                accM[0][nt] = __builtin_amdgcn_mfma_f32_16x16x32_bf16(a0, bm_, accM[0][nt], 0, 0, 0);
                accM[1][nt] = __builtin_amdgcn_mfma_f32_16x16x32_bf16(a1, bm_, accM[1][nt], 0, 0, 0);
                accL[0][nt] = __builtin_amdgcn_mfma_f32_16x16x32_bf16(a0, bl_, accL[0][nt], 0, 0, 0);
                accL[1][nt] = __builtin_amdgcn_mfma_f32_16x16x32_bf16(a1, bl_, accL[1][nt], 0, 0, 0);
            }
        }
        __syncthreads();
    }

    const int col_l = lane & 15;
    const int row_q = (lane >> 4) * 4;
    #pragma unroll
    for (int mt = 0; mt < 2; ++mt) {
        #pragma unroll
        for (int nt = 0; nt < 4; ++nt) {
            int col = bn + nt * 16 + col_l;
            float bM = bmu[col];
            float bL = blv[col];
            #pragma unroll
            for (int i = 0; i < 4; ++i) {
                int row = bm + wave * 32 + mt * 16 + row_q + i;
                if (row < M) {
                    size_t idx = (size_t)row * Nc + col;
                    float vm = accM[mt][nt][i] + bM;
                    float vl = accL[mt][nt][i] + bL;
                    mu[idx] = vm;
                    lv[idx] = vl;
                    amvo[idx] = vm + eps[idx] * expf(0.5f * vl);
                }
            }
        }
    }
}

// ------------------------- FC layers (fp32, latency-optimized) -------------
__global__ __launch_bounds__(256) void k_fc1(const float* __restrict__ x2,
                                             const float* __restrict__ W,
                                             const float* __restrict__ bias,
                                             float* __restrict__ hid,
                                             int K, int Nc) {
    const int m = blockIdx.x;
    const int t = threadIdx.x;
    __shared__ float sx[256];
    for (int k = t; k < K; k += 256) sx[k] = x2[(size_t)m * K + k];
    __syncthreads();
    const int nc4 = Nc >> 2;
    const float4* Wv = (const float4*)W;
    float4 acc = make_float4(0.f, 0.f, 0.f, 0.f);
    #pragma unroll 4
    for (int k = 0; k < K; ++k) {
        float a = sx[k];
        float4 w = Wv[(size_t)k * nc4 + t];
        acc.x += a * w.x; acc.y += a * w.y;
        acc.z += a * w.z; acc.w += a * w.w;
    }
    float4 b = ((const float4*)bias)[t];
    float4 r;
    r.x = fmaxf(acc.x + b.x, 0.f);
    r.y = fmaxf(acc.y + b.y, 0.f);
    r.z = fmaxf(acc.z + b.z, 0.f);
    r.w = fmaxf(acc.w + b.w, 0.f);
    ((float4*)hid)[(size_t)m * nc4 + t] = r;
}

__global__ __launch_bounds__(128) void k_fc2(const float* __restrict__ hid,
                                             const float* __restrict__ W,
                                             const float* __restrict__ bias,
                                             float* __restrict__ out,
                                             int K, int Nc) {
    const int m = blockIdx.x;
    const int c = threadIdx.x;
    __shared__ float sh[1024];
    for (int k = c; k < K; k += 128) sh[k] = hid[(size_t)m * K + k];
    __syncthreads();
    float a0 = 0.f, a1 = 0.f, a2 = 0.f, a3 = 0.f;
    for (int k = 0; k < K; k += 4) {
        a0 += sh[k    ] * W[(size_t)(k    ) * Nc + c];
        a1 += sh[k + 1] * W[(size_t)(k + 1) * Nc + c];
        a2 += sh[k + 2] * W[(size_t)(k + 2) * Nc + c];
        a3 += sh[k + 3] * W[(size_t)(k + 3) * Nc + c];
    }
    out[(size_t)m * Nc + c] = (a0 + a1) + (a2 + a3) + bias[c];
}

// ------------------------- misc --------------------------------------------

__global__ void k_gstart(const int* __restrict__ batch, int* __restrict__ gstart, int Nn, int B) {
    int b = blockIdx.x * blockDim.x + threadIdx.x;
    if (b > B) return;
    int lo = 0, hi = Nn;
    while (lo < hi) {
        int mid = (lo + hi) >> 1;
        if (batch[mid] < b) lo = mid + 1; else hi = mid;
    }
    gstart[b] = lo;
}

// max-pool over bf16 h3 -> fp32 x2.
// grid (B, F/64), block (64, 4): 4-way row parallelism + LDS tree reduce.
__global__ void k_pool_max(const unsigned short* __restrict__ h, const int* __restrict__ gstart,
                           float* __restrict__ x2, int F) {
    int b = blockIdx.x;
    int c = blockIdx.y * 64 + threadIdx.x;
    int s = gstart[b], e = gstart[b + 1];
    float mv = -INFINITY;
    for (int i = s + threadIdx.y; i < e; i += 4)
        mv = fmaxf(mv, bf2f(h[(size_t)i * F + c]));
    __shared__ float red[4][64];
    red[threadIdx.y][threadIdx.x] = mv;
    __syncthreads();
    if (threadIdx.y == 0) {
        mv = fmaxf(fmaxf(red[0][threadIdx.x], red[1][threadIdx.x]),
                   fmaxf(red[2][threadIdx.x], red[3][threadIdx.x]));
        x2[(size_t)b * F + c] = mv;
    }
}

static inline int ceil_div(int a, int b) { return (a + b - 1) / b; }

extern "C" void kernel_launch(void* const* d_in, const int* in_sizes, int n_in,
                              void* d_out, int out_size, void* d_ws, size_t ws_size,
                              hipStream_t stream) {
    const int F0 = 64;
    const int N = in_sizes[0] / F0;            // 100000
    const int E = in_sizes[1] / 2;             // 400000
    const int F4 = 4 * F0;                     // 256
    const int B = (out_size - 3 * N * F4) / 128;  // 512
    const int M = E + N;

    const float* x     = (const float*)d_in[0];
    const int*   ei    = (const int*)d_in[1];
    const int*   batch = (const int*)d_in[2];
    const float* eps   = (const float*)d_in[3];
    const float* W1  = (const float*)d_in[4];  const float* b1  = (const float*)d_in[5];
    const float* W2  = (const float*)d_in[6];  const float* b2  = (const float*)d_in[7];
    const float* W3  = (const float*)d_in[8];  const float* b3  = (const float*)d_in[9];
    const float* Wmu = (const float*)d_in[10]; const float* bmu = (const float*)d_in[11];
    const float* Wlv = (const float*)d_in[12]; const float* blv = (const float*)d_in[13];
    const float* fc1w = (const float*)d_in[14]; const float* fc1b = (const float*)d_in[15];
    const float* fc2w = (const float*)d_in[16]; const float* fc2b = (const float*)d_in[17];

    const int* e_row = ei;
    const int* e_col = ei + E;

    float* out  = (float*)d_out;
    float* amvo = out;
    float* mu   = out + (size_t)N * F4;
    float* lv   = out + 2 * (size_t)N * F4;
    float* pmvo = out + 3 * (size_t)N * F4;

    // --- workspace carve ---
    char* w = (char*)d_ws;
    auto alloc = [&](size_t bytes) -> void* {
        void* p = (void*)w;
        w += (bytes + 255) & ~(size_t)255;
        return p;
    };
    float* dinv    = (float*)alloc((size_t)N * 4);
    int*   counts  = (int*)alloc((size_t)N * 4);
    int*   offsets = (int*)alloc((size_t)(N + 1) * 4);
    int*   csr_row = (int*)alloc((size_t)M * 4);
    float* csr_nrm = (float*)alloc((size_t)M * 4);
    int*   gstart  = (int*)alloc((size_t)(B + 1) * 4);
    unsigned short* xb  = (unsigned short*)alloc((size_t)N * F0 * 2);
    unsigned short* h1  = (unsigned short*)alloc((size_t)N * 128 * 2);
    unsigned short* h2  = (unsigned short*)alloc((size_t)N * 192 * 2);
    unsigned short* h3  = (unsigned short*)alloc((size_t)N * 256 * 2);
    unsigned short* g   = (unsigned short*)alloc((size_t)N * 256 * 2);  // reused g1..g4
    unsigned short* wt1 = (unsigned short*)alloc((size_t)64 * 128 * 2);
    unsigned short* wt2 = (unsigned short*)alloc((size_t)128 * 192 * 2);
    unsigned short* wt3 = (unsigned short*)alloc((size_t)192 * 256 * 2);
    unsigned short* wtm = (unsigned short*)alloc((size_t)256 * 256 * 2);
    unsigned short* wtl = (unsigned short*)alloc((size_t)256 * 256 * 2);
    float* x2  = (float*)alloc((size_t)B * F4 * 4);
    float* hid = (float*)alloc((size_t)B * 1024 * 4);
    (void)ws_size; (void)n_in;

    // --- 1. graph structure ---
    hipMemsetAsync(counts, 0, (size_t)N * 4, stream);
    k_count<<<ceil_div(E, THREADS), THREADS, 0, stream>>>(e_col, counts, E);
    k_dinv<<<ceil_div(N, THREADS), THREADS, 0, stream>>>(counts, dinv, N);
    k_scan<<<1, 1024, 0, stream>>>(counts, offsets, N);
    k_init_cursor<<<ceil_div(N, THREADS), THREADS, 0, stream>>>(offsets, counts, N);
    k_scatter<<<ceil_div(E + N, THREADS), THREADS, 0, stream>>>(
        e_row, e_col, dinv, counts, csr_row, csr_nrm, E, N);

    // --- 2. casts + weight prep ---
    k_cast_bf16<<<ceil_div(N * F0, THREADS), THREADS, 0, stream>>>(x, xb, N * F0);
    k_prep_w<<<ceil_div(64 * 128, THREADS), THREADS, 0, stream>>>(W1, wt1, 64, 128);
    k_prep_w<<<ceil_div(128 * 192, THREADS), THREADS, 0, stream>>>(W2, wt2, 128, 192);
    k_prep_w<<<ceil_div(192 * 256, THREADS), THREADS, 0, stream>>>(W3, wt3, 192, 256);
    k_prep_w<<<ceil_div(256 * 256, THREADS), THREADS, 0, stream>>>(Wmu, wtm, 256, 256);
    k_prep_w<<<ceil_div(256 * 256, THREADS), THREADS, 0, stream>>>(Wlv, wtl, 256, 256);

    // --- 3. GCN stack: agg -> transform ---
    // g1 = agg(xb) [N,64]; h1 = relu(g1@W1+b1) [N,128]
    {
        dim3 blk(8, 32); // 64ch
        k_agg<<<ceil_div(N, 32), blk, 0, stream>>>(xb, offsets, csr_row, csr_nrm, g, N, 64);
        dim3 gg(ceil_div(N, GBM), 128 / GBN);
        k_gemm_mfma<<<gg, 256, 0, stream>>>(g, wt1, b1, h1, N, 64, 128, 1, 1);
    }
    // g2 = agg(h1) [N,128]; h2 = relu(g2@W2+b2) [N,192]
    {
        dim3 blk(16, 16);
        k_agg<<<ceil_div(N, 16), blk, 0, stream>>>(h1, offsets, csr_row, csr_nrm, g, N, 128);
        dim3 gg(ceil_div(N, GBM), 192 / GBN);
        k_gemm_mfma<<<gg, 256, 0, stream>>>(g, wt2, b2, h2, N, 128, 192, 1, 1);
    }
    // g3 = agg(h2) [N,192]; h3 = relu(g3@W3+b3) [N,256]
    {
        dim3 blk(24, 8);
        k_agg<<<ceil_div(N, 8), blk, 0, stream>>>(h2, offsets, csr_row, csr_nrm, g, N, 192);
        dim3 gg(ceil_div(N, GBM), 256 / GBN);
        k_gemm_mfma<<<gg, 256, 0, stream>>>(g, wt3, b3, h3, N, 192, 256, 1, 1);
    }
    // g4 = agg(h3) [N,256]; fused: mu, lv, amvo in one pass
    {
        dim3 blk(32, 8);
        k_agg<<<ceil_div(N, 8), blk, 0, stream>>>(h3, offsets, csr_row, csr_nrm, g, N, 256);
        dim3 gg(ceil_div(N, GBM), 256 / GBN);
        k_gemm_mfma_dual<<<gg, 256, 0, stream>>>(g, wtm, wtl, bmu, blv, eps,
                                                 mu, lv, amvo, N, 256, 256);
    }

    // --- 4. pool + MLP (fp32) ---
    k_gstart<<<ceil_div(B + 1, THREADS), THREADS, 0, stream>>>(batch, gstart, N, B);
    {
        dim3 gg(B, F4 / 64);
        dim3 blk(64, 4);
        k_pool_max<<<gg, blk, 0, stream>>>(h3, gstart, x2, F4);
    }
    k_fc1<<<B, 256, 0, stream>>>(x2, fc1w, fc1b, hid, F4, 1024);
    k_fc2<<<B, 128, 0, stream>>>(hid, fc2w, fc2b, pmvo, 1024, 128);
}

// Round 3
// 1107.797 us; speedup vs baseline: 1.2324x; 1.0412x over previous
//
#include <hip/hip_runtime.h>
#include <hip/hip_bf16.h>
#include <math.h>

// ---------------------------------------------------------------------------
// GCN-VAE encoder, round 5.
// r4 rocprof: k_gemm_mfma_dual = 232us, MfmaUtil 4.5%, VALU 12%, HBM 2.4TB/s,
// occupancy 31% -> latency-bound, VGPR-capped (64 acc f32/lane + staging
// ~= 140 regs = 3 waves/SIMD). Neither MFMA (~10us) nor LDS (~9us) nor HBM
// floor (~75us) explains 232us; concurrency does.
// Change: MFMA GEMMs go 4 waves x 32 rows -> 8 waves (512 thr) x 16 rows.
// Same 128x64 tile, same MFMA order per output element (bit-identical),
// half the accumulators per lane (dual 64->32 f32) -> ~5-6 waves/SIMD,
// LDS cap 4 blocks x 8 waves = 32 waves/CU. Epilogue work per lane halves.
// ---------------------------------------------------------------------------

#define THREADS 256

typedef short s8v __attribute__((ext_vector_type(8)));   // 8 bf16 = 4 VGPR
typedef float f4v __attribute__((ext_vector_type(4)));   // MFMA accum

__device__ inline float bf_lo(unsigned int u) {
    union { unsigned int i; float f; } c; c.i = u << 16; return c.f;
}
__device__ inline float bf_hi(unsigned int u) {
    union { unsigned int i; float f; } c; c.i = u & 0xffff0000u; return c.f;
}
__device__ inline unsigned short f2bf(float f) {
    __hip_bfloat16 h = __float2bfloat16(f);
    return *reinterpret_cast<unsigned short*>(&h);
}
__device__ inline float bf2f(unsigned short u) {
    union { unsigned int i; float f; } c; c.i = ((unsigned int)u) << 16; return c.f;
}

// ------------------------- graph structure ---------------------------------

__global__ void k_count(const int* __restrict__ col, int* __restrict__ counts, int E) {
    int e = blockIdx.x * blockDim.x + threadIdx.x;
    if (e < E) atomicAdd(&counts[col[e]], 1);
}

__global__ void k_dinv(const int* __restrict__ counts, float* __restrict__ dinv, int N) {
    int i = blockIdx.x * blockDim.x + threadIdx.x;
    if (i < N) dinv[i] = rsqrtf((float)(counts[i] + 1));   // +1 self loop
}

__global__ __launch_bounds__(1024) void k_scan(const int* __restrict__ counts,
                                               int* __restrict__ offsets, int N) {
    __shared__ int ssum[1024];
    int tid = threadIdx.x;
    int chunk = (N + 1023) / 1024;
    int begin = tid * chunk;
    int end = begin + chunk; if (end > N) end = N;
    int s = 0;
    for (int i = begin; i < end; ++i) s += counts[i] + 1;
    ssum[tid] = s;
    __syncthreads();
    for (int off = 1; off < 1024; off <<= 1) {
        int v = 0;
        if (tid >= off) v = ssum[tid - off];
        __syncthreads();
        if (tid >= off) ssum[tid] += v;
        __syncthreads();
    }
    int prefix = (tid == 0) ? 0 : ssum[tid - 1];
    for (int i = begin; i < end; ++i) {
        offsets[i] = prefix;
        prefix += counts[i] + 1;
    }
    if (end == N && begin < N) offsets[N] = prefix;
}

__global__ void k_init_cursor(const int* __restrict__ offsets, int* __restrict__ cursor, int N) {
    int i = blockIdx.x * blockDim.x + threadIdx.x;
    if (i < N) cursor[i] = offsets[i];
}

__global__ void k_scatter(const int* __restrict__ row, const int* __restrict__ col,
                          const float* __restrict__ dinv, int* __restrict__ cursor,
                          int* __restrict__ csr_row, float* __restrict__ csr_norm,
                          int E, int N) {
    int e = blockIdx.x * blockDim.x + threadIdx.x;
    if (e < E) {
        int r = row[e], c = col[e];
        int slot = atomicAdd(&cursor[c], 1);
        csr_row[slot] = r;
        csr_norm[slot] = dinv[r] * dinv[c];
    } else if (e < E + N) {
        int i = e - E;
        int slot = atomicAdd(&cursor[i], 1);
        csr_row[slot] = i;
        float d = dinv[i];
        csr_norm[slot] = d * d;
    }
}

// ------------------------- casts / weight prep -----------------------------

__global__ void k_cast_bf16(const float* __restrict__ src, unsigned short* __restrict__ dst, int n) {
    int i = blockIdx.x * blockDim.x + threadIdx.x;
    if (i < n) dst[i] = f2bf(src[i]);
}

// W [K,Nc] fp32 -> WT [Nc,K] bf16
__global__ void k_prep_w(const float* __restrict__ W, unsigned short* __restrict__ WT,
                         int K, int Nc) {
    int id = blockIdx.x * blockDim.x + threadIdx.x;
    if (id < K * Nc) {
        int k = id / Nc, n = id % Nc;
        WT[(size_t)n * K + k] = f2bf(W[id]);
    }
}

// ------------------------- aggregation (gather, bf16 in/out) ---------------
// block: (F/8, nodes_per_block). Each thread owns 8 channels of one node.
__global__ void k_agg(const unsigned short* __restrict__ h,
                      const int* __restrict__ offsets,
                      const int* __restrict__ csr_row,
                      const float* __restrict__ csr_nrm,
                      unsigned short* __restrict__ g, int N, int F) {
    int node = blockIdx.x * blockDim.y + threadIdx.y;
    if (node >= N) return;
    int c8 = threadIdx.x * 8;
    int off0 = offsets[node], off1 = offsets[node + 1];
    float a0=0.f,a1=0.f,a2=0.f,a3=0.f,a4=0.f,a5=0.f,a6=0.f,a7=0.f;
    for (int sl = off0; sl < off1; ++sl) {
        int r = csr_row[sl];
        float w = csr_nrm[sl];
        uint4 v = *(const uint4*)(h + (size_t)r * F + c8);
        a0 += w * bf_lo(v.x); a1 += w * bf_hi(v.x);
        a2 += w * bf_lo(v.y); a3 += w * bf_hi(v.y);
        a4 += w * bf_lo(v.z); a5 += w * bf_hi(v.z);
        a6 += w * bf_lo(v.w); a7 += w * bf_hi(v.w);
    }
    uint4 o;
    o.x = (unsigned)f2bf(a0) | ((unsigned)f2bf(a1) << 16);
    o.y = (unsigned)f2bf(a2) | ((unsigned)f2bf(a3) << 16);
    o.z = (unsigned)f2bf(a4) | ((unsigned)f2bf(a5) << 16);
    o.w = (unsigned)f2bf(a6) | ((unsigned)f2bf(a7) << 16);
    *(uint4*)(g + (size_t)node * F + c8) = o;
}

// ------------------------- bf16 MFMA GEMM ----------------------------------
// C[M,Nc] = A[M,K](bf16) @ W (given as WT[Nc,K] bf16), +bias, opt relu.
// Out fp32 or bf16. BM=128, BN=64, BK=64, 512 threads = 8 waves x 16 rows.
#define GBM 128
#define GBN 64
#define GBK 64
#define LDP 72   // padded LDS row stride (shorts)

__global__ __launch_bounds__(512) void k_gemm_mfma(
    const unsigned short* __restrict__ A,
    const unsigned short* __restrict__ WT,
    const float* __restrict__ bias,
    void* __restrict__ Cout, int M, int K, int Nc,
    int dorelu, int out_bf16) {
    __shared__ unsigned short sA[GBM * LDP];
    __shared__ unsigned short sB[GBN * LDP];
    const int tid = threadIdx.x;
    const int wave = tid >> 6;          // 0..7, owns 16 rows
    const int lane = tid & 63;
    const int bm = blockIdx.x * GBM;
    const int bn = blockIdx.y * GBN;

    f4v acc[4];
    #pragma unroll
    for (int j = 0; j < 4; ++j) acc[j] = (f4v){0.f, 0.f, 0.f, 0.f};

    const int lrow = tid >> 3;          // 0..63
    const int lk = (tid & 7) * 8;       // 0,8,...,56
    const int fr = lane & 15;
    const int fk = (lane >> 4) * 8;

    for (int k0 = 0; k0 < K; k0 += GBK) {
        #pragma unroll
        for (int p = 0; p < 2; ++p) {
            int r = lrow + p * 64;
            int gm = bm + r;
            uint4 v = make_uint4(0u, 0u, 0u, 0u);
            if (gm < M) v = *(const uint4*)(A + (size_t)gm * K + k0 + lk);
            *(uint4*)(&sA[r * LDP + lk]) = v;
        }
        {
            uint4 v = *(const uint4*)(WT + (size_t)(bn + lrow) * K + k0 + lk);
            *(uint4*)(&sB[lrow * LDP + lk]) = v;
        }
        __syncthreads();
        #pragma unroll
        for (int ks = 0; ks < 2; ++ks) {
            s8v a0 = *(const s8v*)(&sA[(wave * 16 + fr) * LDP + ks * 32 + fk]);
            #pragma unroll
            for (int nt = 0; nt < 4; ++nt) {
                s8v b = *(const s8v*)(&sB[(nt * 16 + fr) * LDP + ks * 32 + fk]);
                acc[nt] = __builtin_amdgcn_mfma_f32_16x16x32_bf16(a0, b, acc[nt], 0, 0, 0);
            }
        }
        __syncthreads();
    }

    const int col_l = lane & 15;
    const int row_q = (lane >> 4) * 4;
    #pragma unroll
    for (int nt = 0; nt < 4; ++nt) {
        #pragma unroll
        for (int i = 0; i < 4; ++i) {
            int row = bm + wave * 16 + row_q + i;
            int col = bn + nt * 16 + col_l;
            if (row < M) {
                float v = acc[nt][i] + bias[col];
                if (dorelu) v = fmaxf(v, 0.f);
                if (out_bf16)
                    ((unsigned short*)Cout)[(size_t)row * Nc + col] = f2bf(v);
                else
                    ((float*)Cout)[(size_t)row * Nc + col] = v;
            }
        }
    }
}

// ------------------------- dual bf16 MFMA GEMM + reparam epilogue ----------
// One pass over A computes mu = A@Wm + bmu and lv = A@Wl + blv for the same
// output tile, then amvo = mu + eps*exp(0.5*lv) in-register.
// 512 threads = 8 waves x 16 rows: 32 acc f32/lane (was 64) -> higher occ.
__global__ __launch_bounds__(512) void k_gemm_mfma_dual(
    const unsigned short* __restrict__ A,
    const unsigned short* __restrict__ WTm,
    const unsigned short* __restrict__ WTl,
    const float* __restrict__ bmu,
    const float* __restrict__ blv,
    const float* __restrict__ eps,
    float* __restrict__ mu,
    float* __restrict__ lv,
    float* __restrict__ amvo,
    int M, int K, int Nc) {
    __shared__ unsigned short sA[GBM * LDP];
    __shared__ unsigned short sBm[GBN * LDP];
    __shared__ unsigned short sBl[GBN * LDP];
    const int tid = threadIdx.x;
    const int wave = tid >> 6;          // 0..7, owns 16 rows
    const int lane = tid & 63;
    const int bm = blockIdx.x * GBM;
    const int bn = blockIdx.y * GBN;

    f4v accM[4], accL[4];
    #pragma unroll
    for (int j = 0; j < 4; ++j) {
        accM[j] = (f4v){0.f, 0.f, 0.f, 0.f};
        accL[j] = (f4v){0.f, 0.f, 0.f, 0.f};
    }

    const int lrow = tid >> 3;          // 0..63
    const int lk = (tid & 7) * 8;       // 0,8,...,56
    const int fr = lane & 15;
    const int fk = (lane >> 4) * 8;

    for (int k0 = 0; k0 < K; k0 += GBK) {
        #pragma unroll
        for (int p = 0; p < 2; ++p) {
            int r = lrow + p * 64;
            int gm = bm + r;
            uint4 v = make_uint4(0u, 0u, 0u, 0u);
            if (gm < M) v = *(const uint4*)(A + (size_t)gm * K + k0 + lk);
            *(uint4*)(&sA[r * LDP + lk]) = v;
        }
        {
            uint4 vm = *(const uint4*)(WTm + (size_t)(bn + lrow) * K + k0 + lk);
            uint4 vl = *(const uint4*)(WTl + (size_t)(bn + lrow) * K + k0 + lk);
            *(uint4*)(&sBm[lrow * LDP + lk]) = vm;
            *(uint4*)(&sBl[lrow * LDP + lk]) = vl;
        }
        __syncthreads();
        #pragma unroll
        for (int ks = 0; ks < 2; ++ks) {
            s8v a0 = *(const s8v*)(&sA[(wave * 16 + fr) * LDP + ks * 32 + fk]);
            #pragma unroll
            for (int nt = 0; nt < 4; ++nt) {
                s8v bm_ = *(const s8v*)(&sBm[(nt * 16 + fr) * LDP + ks * 32 + fk]);
                s8v bl_ = *(const s8v*)(&sBl[(nt * 16 + fr) * LDP + ks * 32 + fk]);
                accM[nt] = __builtin_amdgcn_mfma_f32_16x16x32_bf16(a0, bm_, accM[nt], 0, 0, 0);
                accL[nt] = __builtin_amdgcn_mfma_f32_16x16x32_bf16(a0, bl_, accL[nt], 0, 0, 0);
            }
        }
        __syncthreads();
    }

    const int col_l = lane & 15;
    const int row_q = (lane >> 4) * 4;
    #pragma unroll
    for (int nt = 0; nt < 4; ++nt) {
        int col = bn + nt * 16 + col_l;
        float bM = bmu[col];
        float bL = blv[col];
        #pragma unroll
        for (int i = 0; i < 4; ++i) {
            int row = bm + wave * 16 + row_q + i;
            if (row < M) {
                size_t idx = (size_t)row * Nc + col;
                float vm = accM[nt][i] + bM;
                float vl = accL[nt][i] + bL;
                mu[idx] = vm;
                lv[idx] = vl;
                amvo[idx] = vm + eps[idx] * expf(0.5f * vl);
            }
        }
    }
}

// ------------------------- FC layers (fp32, latency-optimized) -------------
__global__ __launch_bounds__(256) void k_fc1(const float* __restrict__ x2,
                                             const float* __restrict__ W,
                                             const float* __restrict__ bias,
                                             float* __restrict__ hid,
                                             int K, int Nc) {
    const int m = blockIdx.x;
    const int t = threadIdx.x;
    __shared__ float sx[256];
    for (int k = t; k < K; k += 256) sx[k] = x2[(size_t)m * K + k];
    __syncthreads();
    const int nc4 = Nc >> 2;
    const float4* Wv = (const float4*)W;
    float4 acc = make_float4(0.f, 0.f, 0.f, 0.f);
    #pragma unroll 4
    for (int k = 0; k < K; ++k) {
        float a = sx[k];
        float4 w = Wv[(size_t)k * nc4 + t];
        acc.x += a * w.x; acc.y += a * w.y;
        acc.z += a * w.z; acc.w += a * w.w;
    }
    float4 b = ((const float4*)bias)[t];
    float4 r;
    r.x = fmaxf(acc.x + b.x, 0.f);
    r.y = fmaxf(acc.y + b.y, 0.f);
    r.z = fmaxf(acc.z + b.z, 0.f);
    r.w = fmaxf(acc.w + b.w, 0.f);
    ((float4*)hid)[(size_t)m * nc4 + t] = r;
}

__global__ __launch_bounds__(128) void k_fc2(const float* __restrict__ hid,
                                             const float* __restrict__ W,
                                             const float* __restrict__ bias,
                                             float* __restrict__ out,
                                             int K, int Nc) {
    const int m = blockIdx.x;
    const int c = threadIdx.x;
    __shared__ float sh[1024];
    for (int k = c; k < K; k += 128) sh[k] = hid[(size_t)m * K + k];
    __syncthreads();
    float a0 = 0.f, a1 = 0.f, a2 = 0.f, a3 = 0.f;
    for (int k = 0; k < K; k += 4) {
        a0 += sh[k    ] * W[(size_t)(k    ) * Nc + c];
        a1 += sh[k + 1] * W[(size_t)(k + 1) * Nc + c];
        a2 += sh[k + 2] * W[(size_t)(k + 2) * Nc + c];
        a3 += sh[k + 3] * W[(size_t)(k + 3) * Nc + c];
    }
    out[(size_t)m * Nc + c] = (a0 + a1) + (a2 + a3) + bias[c];
}

// ------------------------- misc --------------------------------------------

__global__ void k_gstart(const int* __restrict__ batch, int* __restrict__ gstart, int Nn, int B) {
    int b = blockIdx.x * blockDim.x + threadIdx.x;
    if (b > B) return;
    int lo = 0, hi = Nn;
    while (lo < hi) {
        int mid = (lo + hi) >> 1;
        if (batch[mid] < b) lo = mid + 1; else hi = mid;
    }
    gstart[b] = lo;
}

// max-pool over bf16 h3 -> fp32 x2.
// grid (B, F/64), block (64, 4): 4-way row parallelism + LDS tree reduce.
__global__ void k_pool_max(const unsigned short* __restrict__ h, const int* __restrict__ gstart,
                           float* __restrict__ x2, int F) {
    int b = blockIdx.x;
    int c = blockIdx.y * 64 + threadIdx.x;
    int s = gstart[b], e = gstart[b + 1];
    float mv = -INFINITY;
    for (int i = s + threadIdx.y; i < e; i += 4)
        mv = fmaxf(mv, bf2f(h[(size_t)i * F + c]));
    __shared__ float red[4][64];
    red[threadIdx.y][threadIdx.x] = mv;
    __syncthreads();
    if (threadIdx.y == 0) {
        mv = fmaxf(fmaxf(red[0][threadIdx.x], red[1][threadIdx.x]),
                   fmaxf(red[2][threadIdx.x], red[3][threadIdx.x]));
        x2[(size_t)b * F + c] = mv;
    }
}

static inline int ceil_div(int a, int b) { return (a + b - 1) / b; }

extern "C" void kernel_launch(void* const* d_in, const int* in_sizes, int n_in,
                              void* d_out, int out_size, void* d_ws, size_t ws_size,
                              hipStream_t stream) {
    const int F0 = 64;
    const int N = in_sizes[0] / F0;            // 100000
    const int E = in_sizes[1] / 2;             // 400000
    const int F4 = 4 * F0;                     // 256
    const int B = (out_size - 3 * N * F4) / 128;  // 512
    const int M = E + N;

    const float* x     = (const float*)d_in[0];
    const int*   ei    = (const int*)d_in[1];
    const int*   batch = (const int*)d_in[2];
    const float* eps   = (const float*)d_in[3];
    const float* W1  = (const float*)d_in[4];  const float* b1  = (const float*)d_in[5];
    const float* W2  = (const float*)d_in[6];  const float* b2  = (const float*)d_in[7];
    const float* W3  = (const float*)d_in[8];  const float* b3  = (const float*)d_in[9];
    const float* Wmu = (const float*)d_in[10]; const float* bmu = (const float*)d_in[11];
    const float* Wlv = (const float*)d_in[12]; const float* blv = (const float*)d_in[13];
    const float* fc1w = (const float*)d_in[14]; const float* fc1b = (const float*)d_in[15];
    const float* fc2w = (const float*)d_in[16]; const float* fc2b = (const float*)d_in[17];

    const int* e_row = ei;
    const int* e_col = ei + E;

    float* out  = (float*)d_out;
    float* amvo = out;
    float* mu   = out + (size_t)N * F4;
    float* lv   = out + 2 * (size_t)N * F4;
    float* pmvo = out + 3 * (size_t)N * F4;

    // --- workspace carve ---
    char* w = (char*)d_ws;
    auto alloc = [&](size_t bytes) -> void* {
        void* p = (void*)w;
        w += (bytes + 255) & ~(size_t)255;
        return p;
    };
    float* dinv    = (float*)alloc((size_t)N * 4);
    int*   counts  = (int*)alloc((size_t)N * 4);
    int*   offsets = (int*)alloc((size_t)(N + 1) * 4);
    int*   csr_row = (int*)alloc((size_t)M * 4);
    float* csr_nrm = (float*)alloc((size_t)M * 4);
    int*   gstart  = (int*)alloc((size_t)(B + 1) * 4);
    unsigned short* xb  = (unsigned short*)alloc((size_t)N * F0 * 2);
    unsigned short* h1  = (unsigned short*)alloc((size_t)N * 128 * 2);
    unsigned short* h2  = (unsigned short*)alloc((size_t)N * 192 * 2);
    unsigned short* h3  = (unsigned short*)alloc((size_t)N * 256 * 2);
    unsigned short* g   = (unsigned short*)alloc((size_t)N * 256 * 2);  // reused g1..g4
    unsigned short* wt1 = (unsigned short*)alloc((size_t)64 * 128 * 2);
    unsigned short* wt2 = (unsigned short*)alloc((size_t)128 * 192 * 2);
    unsigned short* wt3 = (unsigned short*)alloc((size_t)192 * 256 * 2);
    unsigned short* wtm = (unsigned short*)alloc((size_t)256 * 256 * 2);
    unsigned short* wtl = (unsigned short*)alloc((size_t)256 * 256 * 2);
    float* x2  = (float*)alloc((size_t)B * F4 * 4);
    float* hid = (float*)alloc((size_t)B * 1024 * 4);
    (void)ws_size; (void)n_in;

    // --- 1. graph structure ---
    hipMemsetAsync(counts, 0, (size_t)N * 4, stream);
    k_count<<<ceil_div(E, THREADS), THREADS, 0, stream>>>(e_col, counts, E);
    k_dinv<<<ceil_div(N, THREADS), THREADS, 0, stream>>>(counts, dinv, N);
    k_scan<<<1, 1024, 0, stream>>>(counts, offsets, N);
    k_init_cursor<<<ceil_div(N, THREADS), THREADS, 0, stream>>>(offsets, counts, N);
    k_scatter<<<ceil_div(E + N, THREADS), THREADS, 0, stream>>>(
        e_row, e_col, dinv, counts, csr_row, csr_nrm, E, N);

    // --- 2. casts + weight prep ---
    k_cast_bf16<<<ceil_div(N * F0, THREADS), THREADS, 0, stream>>>(x, xb, N * F0);
    k_prep_w<<<ceil_div(64 * 128, THREADS), THREADS, 0, stream>>>(W1, wt1, 64, 128);
    k_prep_w<<<ceil_div(128 * 192, THREADS), THREADS, 0, stream>>>(W2, wt2, 128, 192);
    k_prep_w<<<ceil_div(192 * 256, THREADS), THREADS, 0, stream>>>(W3, wt3, 192, 256);
    k_prep_w<<<ceil_div(256 * 256, THREADS), THREADS, 0, stream>>>(Wmu, wtm, 256, 256);
    k_prep_w<<<ceil_div(256 * 256, THREADS), THREADS, 0, stream>>>(Wlv, wtl, 256, 256);

    // --- 3. GCN stack: agg -> transform ---
    // g1 = agg(xb) [N,64]; h1 = relu(g1@W1+b1) [N,128]
    {
        dim3 blk(8, 32); // 64ch
        k_agg<<<ceil_div(N, 32), blk, 0, stream>>>(xb, offsets, csr_row, csr_nrm, g, N, 64);
        dim3 gg(ceil_div(N, GBM), 128 / GBN);
        k_gemm_mfma<<<gg, 512, 0, stream>>>(g, wt1, b1, h1, N, 64, 128, 1, 1);
    }
    // g2 = agg(h1) [N,128]; h2 = relu(g2@W2+b2) [N,192]
    {
        dim3 blk(16, 16);
        k_agg<<<ceil_div(N, 16), blk, 0, stream>>>(h1, offsets, csr_row, csr_nrm, g, N, 128);
        dim3 gg(ceil_div(N, GBM), 192 / GBN);
        k_gemm_mfma<<<gg, 512, 0, stream>>>(g, wt2, b2, h2, N, 128, 192, 1, 1);
    }
    // g3 = agg(h2) [N,192]; h3 = relu(g3@W3+b3) [N,256]
    {
        dim3 blk(24, 8);
        k_agg<<<ceil_div(N, 8), blk, 0, stream>>>(h2, offsets, csr_row, csr_nrm, g, N, 192);
        dim3 gg(ceil_div(N, GBM), 256 / GBN);
        k_gemm_mfma<<<gg, 512, 0, stream>>>(g, wt3, b3, h3, N, 192, 256, 1, 1);
    }
    // g4 = agg(h3) [N,256]; fused: mu, lv, amvo in one pass
    {
        dim3 blk(32, 8);
        k_agg<<<ceil_div(N, 8), blk, 0, stream>>>(h3, offsets, csr_row, csr_nrm, g, N, 256);
        dim3 gg(ceil_div(N, GBM), 256 / GBN);
        k_gemm_mfma_dual<<<gg, 512, 0, stream>>>(g, wtm, wtl, bmu, blv, eps,
                                                 mu, lv, amvo, N, 256, 256);
    }

    // --- 4. pool + MLP (fp32) ---
    k_gstart<<<ceil_div(B + 1, THREADS), THREADS, 0, stream>>>(batch, gstart, N, B);
    {
        dim3 gg(B, F4 / 64);
        dim3 blk(64, 4);
        k_pool_max<<<gg, blk, 0, stream>>>(h3, gstart, x2, F4);
    }
    k_fc1<<<B, 256, 0, stream>>>(x2, fc1w, fc1b, hid, F4, 1024);
    k_fc2<<<B, 128, 0, stream>>>(hid, fc2w, fc2b, pmvo, 1024, 128);
}

// Round 4
// 1096.192 us; speedup vs baseline: 1.2454x; 1.0106x over previous
//
#include <hip/hip_runtime.h>
#include <hip/hip_bf16.h>
#include <math.h>

// ---------------------------------------------------------------------------
// GCN-VAE encoder, round 6.
// r5 rocprof: dual = 192us, occ 60%, MfmaUtil 5.4%, HBM 2.9TB/s -> nothing
// saturated; the 2-barrier-per-K-step loop (only 4 K-steps) drains vmcnt(0)
// at every barrier. Fix: B (64xK bf16 <= 34KB) is staged in LDS ONCE, whole;
// A fragments stream global->reg (16 rows x 64B per wave-step, L2-friendly).
// K-loop has ZERO barriers. XCD-grouped block decode puts the NB bn-siblings
// of each bm on one XCD so A re-reads hit that XCD's L2.
// MFMA operand values/order unchanged -> bit-identical outputs.
// ---------------------------------------------------------------------------

#define THREADS 256

typedef short s8v __attribute__((ext_vector_type(8)));   // 8 bf16 = 4 VGPR
typedef float f4v __attribute__((ext_vector_type(4)));   // MFMA accum

__device__ inline float bf_lo(unsigned int u) {
    union { unsigned int i; float f; } c; c.i = u << 16; return c.f;
}
__device__ inline float bf_hi(unsigned int u) {
    union { unsigned int i; float f; } c; c.i = u & 0xffff0000u; return c.f;
}
__device__ inline unsigned short f2bf(float f) {
    __hip_bfloat16 h = __float2bfloat16(f);
    return *reinterpret_cast<unsigned short*>(&h);
}
__device__ inline float bf2f(unsigned short u) {
    union { unsigned int i; float f; } c; c.i = ((unsigned int)u) << 16; return c.f;
}

// ------------------------- graph structure ---------------------------------

__global__ void k_count(const int* __restrict__ col, int* __restrict__ counts, int E) {
    int e = blockIdx.x * blockDim.x + threadIdx.x;
    if (e < E) atomicAdd(&counts[col[e]], 1);
}

__global__ void k_dinv(const int* __restrict__ counts, float* __restrict__ dinv, int N) {
    int i = blockIdx.x * blockDim.x + threadIdx.x;
    if (i < N) dinv[i] = rsqrtf((float)(counts[i] + 1));   // +1 self loop
}

__global__ __launch_bounds__(1024) void k_scan(const int* __restrict__ counts,
                                               int* __restrict__ offsets, int N) {
    __shared__ int ssum[1024];
    int tid = threadIdx.x;
    int chunk = (N + 1023) / 1024;
    int begin = tid * chunk;
    int end = begin + chunk; if (end > N) end = N;
    int s = 0;
    for (int i = begin; i < end; ++i) s += counts[i] + 1;
    ssum[tid] = s;
    __syncthreads();
    for (int off = 1; off < 1024; off <<= 1) {
        int v = 0;
        if (tid >= off) v = ssum[tid - off];
        __syncthreads();
        if (tid >= off) ssum[tid] += v;
        __syncthreads();
    }
    int prefix = (tid == 0) ? 0 : ssum[tid - 1];
    for (int i = begin; i < end; ++i) {
        offsets[i] = prefix;
        prefix += counts[i] + 1;
    }
    if (end == N && begin < N) offsets[N] = prefix;
}

__global__ void k_init_cursor(const int* __restrict__ offsets, int* __restrict__ cursor, int N) {
    int i = blockIdx.x * blockDim.x + threadIdx.x;
    if (i < N) cursor[i] = offsets[i];
}

__global__ void k_scatter(const int* __restrict__ row, const int* __restrict__ col,
                          const float* __restrict__ dinv, int* __restrict__ cursor,
                          int* __restrict__ csr_row, float* __restrict__ csr_norm,
                          int E, int N) {
    int e = blockIdx.x * blockDim.x + threadIdx.x;
    if (e < E) {
        int r = row[e], c = col[e];
        int slot = atomicAdd(&cursor[c], 1);
        csr_row[slot] = r;
        csr_norm[slot] = dinv[r] * dinv[c];
    } else if (e < E + N) {
        int i = e - E;
        int slot = atomicAdd(&cursor[i], 1);
        csr_row[slot] = i;
        float d = dinv[i];
        csr_norm[slot] = d * d;
    }
}

// ------------------------- casts / weight prep -----------------------------

__global__ void k_cast_bf16(const float* __restrict__ src, unsigned short* __restrict__ dst, int n) {
    int i = blockIdx.x * blockDim.x + threadIdx.x;
    if (i < n) dst[i] = f2bf(src[i]);
}

// W [K,Nc] fp32 -> WT [Nc,K] bf16
__global__ void k_prep_w(const float* __restrict__ W, unsigned short* __restrict__ WT,
                         int K, int Nc) {
    int id = blockIdx.x * blockDim.x + threadIdx.x;
    if (id < K * Nc) {
        int k = id / Nc, n = id % Nc;
        WT[(size_t)n * K + k] = f2bf(W[id]);
    }
}

// ------------------------- aggregation (gather, bf16 in/out) ---------------
// block: (F/8, nodes_per_block). Each thread owns 8 channels of one node.
__global__ void k_agg(const unsigned short* __restrict__ h,
                      const int* __restrict__ offsets,
                      const int* __restrict__ csr_row,
                      const float* __restrict__ csr_nrm,
                      unsigned short* __restrict__ g, int N, int F) {
    int node = blockIdx.x * blockDim.y + threadIdx.y;
    if (node >= N) return;
    int c8 = threadIdx.x * 8;
    int off0 = offsets[node], off1 = offsets[node + 1];
    float a0=0.f,a1=0.f,a2=0.f,a3=0.f,a4=0.f,a5=0.f,a6=0.f,a7=0.f;
    for (int sl = off0; sl < off1; ++sl) {
        int r = csr_row[sl];
        float w = csr_nrm[sl];
        uint4 v = *(const uint4*)(h + (size_t)r * F + c8);
        a0 += w * bf_lo(v.x); a1 += w * bf_hi(v.x);
        a2 += w * bf_lo(v.y); a3 += w * bf_hi(v.y);
        a4 += w * bf_lo(v.z); a5 += w * bf_hi(v.z);
        a6 += w * bf_lo(v.w); a7 += w * bf_hi(v.w);
    }
    uint4 o;
    o.x = (unsigned)f2bf(a0) | ((unsigned)f2bf(a1) << 16);
    o.y = (unsigned)f2bf(a2) | ((unsigned)f2bf(a3) << 16);
    o.z = (unsigned)f2bf(a4) | ((unsigned)f2bf(a5) << 16);
    o.w = (unsigned)f2bf(a6) | ((unsigned)f2bf(a7) << 16);
    *(uint4*)(g + (size_t)node * F + c8) = o;
}

// ------------------------- bf16 MFMA GEMM ----------------------------------
// C[M,Nc] = A[M,K](bf16) @ W (WT[Nc,K] bf16), +bias, opt relu.
// BM=128, BN=64, 512 threads = 8 waves x 16 rows. FULL B staged in LDS once
// (64 x K bf16 <= 34KB), then a barrier-free K-loop: A fragments stream
// global->reg. Block decode groups the NB bn-siblings of one bm on one XCD.
#define GBM 128
#define GBN 64
#define GBK 64
#define LDBMAX 264   // max (K+8) shorts: K<=256; stride%32dw==4 -> 2-way only

__global__ __launch_bounds__(512) void k_gemm_mfma(
    const unsigned short* __restrict__ A,
    const unsigned short* __restrict__ WT,
    const float* __restrict__ bias,
    void* __restrict__ Cout, int M, int K, int Nc,
    int dorelu, int out_bf16) {
    __shared__ unsigned short sB[64 * LDBMAX];
    const int tid = threadIdx.x;
    const int wave = tid >> 6;          // 0..7, owns 16 rows
    const int lane = tid & 63;

    // XCD-grouped decode: NB bn-blocks of one bm -> same XCD (id%8 const)
    const int nbm = (M + GBM - 1) / GBM;
    const int NB = Nc >> 6;
    const int grpsz = 8 * NB;
    const int id = blockIdx.x;
    const int bmi = (id / grpsz) * 8 + (id % 8);
    const int bni = (id % grpsz) >> 3;
    if (bmi >= nbm) return;
    const int bm = bmi * GBM;
    const int bn = bni * GBN;

    const int ldb = K + 8;
    // stage full B once
    const int kc8 = K >> 3;             // uint4 chunks per row
    for (int l = tid; l < 64 * kc8; l += 512) {
        int row = l / kc8, kc = (l - row * kc8) * 8;
        *(uint4*)(&sB[row * ldb + kc]) =
            *(const uint4*)(WT + (size_t)(bn + row) * K + kc);
    }
    __syncthreads();

    f4v acc[4];
    #pragma unroll
    for (int j = 0; j < 4; ++j) acc[j] = (f4v){0.f, 0.f, 0.f, 0.f};

    const int fr = lane & 15;
    const int fk = (lane >> 4) * 8;
    const int gm = bm + wave * 16 + fr;
    const unsigned short* Arow = A + (size_t)gm * K;
    const bool inM = (gm < M);

    for (int k0 = 0; k0 < K; k0 += GBK) {
        #pragma unroll
        for (int ks = 0; ks < 2; ++ks) {
            int kk = k0 + ks * 32 + fk;
            s8v a0 = inM ? *(const s8v*)(Arow + kk)
                         : (s8v){0, 0, 0, 0, 0, 0, 0, 0};
            #pragma unroll
            for (int nt = 0; nt < 4; ++nt) {
                s8v b = *(const s8v*)(&sB[(nt * 16 + fr) * ldb + kk]);
                acc[nt] = __builtin_amdgcn_mfma_f32_16x16x32_bf16(a0, b, acc[nt], 0, 0, 0);
            }
        }
    }

    const int col_l = lane & 15;
    const int row_q = (lane >> 4) * 4;
    #pragma unroll
    for (int nt = 0; nt < 4; ++nt) {
        #pragma unroll
        for (int i = 0; i < 4; ++i) {
            int row = bm + wave * 16 + row_q + i;
            int col = bn + nt * 16 + col_l;
            if (row < M) {
                float v = acc[nt][i] + bias[col];
                if (dorelu) v = fmaxf(v, 0.f);
                if (out_bf16)
                    ((unsigned short*)Cout)[(size_t)row * Nc + col] = f2bf(v);
                else
                    ((float*)Cout)[(size_t)row * Nc + col] = v;
            }
        }
    }
}

// ------------------------- dual bf16 MFMA GEMM + reparam epilogue ----------
// mu = A@Wm + bmu, lv = A@Wl + blv, amvo = mu + eps*exp(0.5*lv), one pass.
// Same barrier-free structure; both full-K B matrices in LDS (67.6KB).
__global__ __launch_bounds__(512) void k_gemm_mfma_dual(
    const unsigned short* __restrict__ A,
    const unsigned short* __restrict__ WTm,
    const unsigned short* __restrict__ WTl,
    const float* __restrict__ bmu,
    const float* __restrict__ blv,
    const float* __restrict__ eps,
    float* __restrict__ mu,
    float* __restrict__ lv,
    float* __restrict__ amvo,
    int M, int K, int Nc) {
    __shared__ unsigned short sBm[64 * LDBMAX];
    __shared__ unsigned short sBl[64 * LDBMAX];
    const int tid = threadIdx.x;
    const int wave = tid >> 6;
    const int lane = tid & 63;

    const int nbm = (M + GBM - 1) / GBM;
    const int NB = Nc >> 6;
    const int grpsz = 8 * NB;
    const int id = blockIdx.x;
    const int bmi = (id / grpsz) * 8 + (id % 8);
    const int bni = (id % grpsz) >> 3;
    if (bmi >= nbm) return;
    const int bm = bmi * GBM;
    const int bn = bni * GBN;

    const int ldb = K + 8;
    const int kc8 = K >> 3;
    for (int l = tid; l < 64 * kc8; l += 512) {
        int row = l / kc8, kc = (l - row * kc8) * 8;
        *(uint4*)(&sBm[row * ldb + kc]) =
            *(const uint4*)(WTm + (size_t)(bn + row) * K + kc);
        *(uint4*)(&sBl[row * ldb + kc]) =
            *(const uint4*)(WTl + (size_t)(bn + row) * K + kc);
    }
    __syncthreads();

    f4v accM[4], accL[4];
    #pragma unroll
    for (int j = 0; j < 4; ++j) {
        accM[j] = (f4v){0.f, 0.f, 0.f, 0.f};
        accL[j] = (f4v){0.f, 0.f, 0.f, 0.f};
    }

    const int fr = lane & 15;
    const int fk = (lane >> 4) * 8;
    const int gm = bm + wave * 16 + fr;
    const unsigned short* Arow = A + (size_t)gm * K;
    const bool inM = (gm < M);

    for (int k0 = 0; k0 < K; k0 += GBK) {
        #pragma unroll
        for (int ks = 0; ks < 2; ++ks) {
            int kk = k0 + ks * 32 + fk;
            s8v a0 = inM ? *(const s8v*)(Arow + kk)
                         : (s8v){0, 0, 0, 0, 0, 0, 0, 0};
            #pragma unroll
            for (int nt = 0; nt < 4; ++nt) {
                s8v bm_ = *(const s8v*)(&sBm[(nt * 16 + fr) * ldb + kk]);
                s8v bl_ = *(const s8v*)(&sBl[(nt * 16 + fr) * ldb + kk]);
                accM[nt] = __builtin_amdgcn_mfma_f32_16x16x32_bf16(a0, bm_, accM[nt], 0, 0, 0);
                accL[nt] = __builtin_amdgcn_mfma_f32_16x16x32_bf16(a0, bl_, accL[nt], 0, 0, 0);
            }
        }
    }

    const int col_l = lane & 15;
    const int row_q = (lane >> 4) * 4;
    #pragma unroll
    for (int nt = 0; nt < 4; ++nt) {
        int col = bn + nt * 16 + col_l;
        float bM = bmu[col];
        float bL = blv[col];
        #pragma unroll
        for (int i = 0; i < 4; ++i) {
            int row = bm + wave * 16 + row_q + i;
            if (row < M) {
                size_t idx = (size_t)row * Nc + col;
                float vm = accM[nt][i] + bM;
                float vl = accL[nt][i] + bL;
                mu[idx] = vm;
                lv[idx] = vl;
                amvo[idx] = vm + eps[idx] * expf(0.5f * vl);
            }
        }
    }
}

// ------------------------- FC layers (fp32, latency-optimized) -------------
__global__ __launch_bounds__(256) void k_fc1(const float* __restrict__ x2,
                                             const float* __restrict__ W,
                                             const float* __restrict__ bias,
                                             float* __restrict__ hid,
                                             int K, int Nc) {
    const int m = blockIdx.x;
    const int t = threadIdx.x;
    __shared__ float sx[256];
    for (int k = t; k < K; k += 256) sx[k] = x2[(size_t)m * K + k];
    __syncthreads();
    const int nc4 = Nc >> 2;
    const float4* Wv = (const float4*)W;
    float4 acc = make_float4(0.f, 0.f, 0.f, 0.f);
    #pragma unroll 4
    for (int k = 0; k < K; ++k) {
        float a = sx[k];
        float4 w = Wv[(size_t)k * nc4 + t];
        acc.x += a * w.x; acc.y += a * w.y;
        acc.z += a * w.z; acc.w += a * w.w;
    }
    float4 b = ((const float4*)bias)[t];
    float4 r;
    r.x = fmaxf(acc.x + b.x, 0.f);
    r.y = fmaxf(acc.y + b.y, 0.f);
    r.z = fmaxf(acc.z + b.z, 0.f);
    r.w = fmaxf(acc.w + b.w, 0.f);
    ((float4*)hid)[(size_t)m * nc4 + t] = r;
}

__global__ __launch_bounds__(128) void k_fc2(const float* __restrict__ hid,
                                             const float* __restrict__ W,
                                             const float* __restrict__ bias,
                                             float* __restrict__ out,
                                             int K, int Nc) {
    const int m = blockIdx.x;
    const int c = threadIdx.x;
    __shared__ float sh[1024];
    for (int k = c; k < K; k += 128) sh[k] = hid[(size_t)m * K + k];
    __syncthreads();
    float a0 = 0.f, a1 = 0.f, a2 = 0.f, a3 = 0.f;
    for (int k = 0; k < K; k += 4) {
        a0 += sh[k    ] * W[(size_t)(k    ) * Nc + c];
        a1 += sh[k + 1] * W[(size_t)(k + 1) * Nc + c];
        a2 += sh[k + 2] * W[(size_t)(k + 2) * Nc + c];
        a3 += sh[k + 3] * W[(size_t)(k + 3) * Nc + c];
    }
    out[(size_t)m * Nc + c] = (a0 + a1) + (a2 + a3) + bias[c];
}

// ------------------------- misc --------------------------------------------

__global__ void k_gstart(const int* __restrict__ batch, int* __restrict__ gstart, int Nn, int B) {
    int b = blockIdx.x * blockDim.x + threadIdx.x;
    if (b > B) return;
    int lo = 0, hi = Nn;
    while (lo < hi) {
        int mid = (lo + hi) >> 1;
        if (batch[mid] < b) lo = mid + 1; else hi = mid;
    }
    gstart[b] = lo;
}

// max-pool over bf16 h3 -> fp32 x2.
// grid (B, F/64), block (64, 4): 4-way row parallelism + LDS tree reduce.
__global__ void k_pool_max(const unsigned short* __restrict__ h, const int* __restrict__ gstart,
                           float* __restrict__ x2, int F) {
    int b = blockIdx.x;
    int c = blockIdx.y * 64 + threadIdx.x;
    int s = gstart[b], e = gstart[b + 1];
    float mv = -INFINITY;
    for (int i = s + threadIdx.y; i < e; i += 4)
        mv = fmaxf(mv, bf2f(h[(size_t)i * F + c]));
    __shared__ float red[4][64];
    red[threadIdx.y][threadIdx.x] = mv;
    __syncthreads();
    if (threadIdx.y == 0) {
        mv = fmaxf(fmaxf(red[0][threadIdx.x], red[1][threadIdx.x]),
                   fmaxf(red[2][threadIdx.x], red[3][threadIdx.x]));
        x2[(size_t)b * F + c] = mv;
    }
}

static inline int ceil_div(int a, int b) { return (a + b - 1) / b; }

extern "C" void kernel_launch(void* const* d_in, const int* in_sizes, int n_in,
                              void* d_out, int out_size, void* d_ws, size_t ws_size,
                              hipStream_t stream) {
    const int F0 = 64;
    const int N = in_sizes[0] / F0;            // 100000
    const int E = in_sizes[1] / 2;             // 400000
    const int F4 = 4 * F0;                     // 256
    const int B = (out_size - 3 * N * F4) / 128;  // 512
    const int M = E + N;

    const float* x     = (const float*)d_in[0];
    const int*   ei    = (const int*)d_in[1];
    const int*   batch = (const int*)d_in[2];
    const float* eps   = (const float*)d_in[3];
    const float* W1  = (const float*)d_in[4];  const float* b1  = (const float*)d_in[5];
    const float* W2  = (const float*)d_in[6];  const float* b2  = (const float*)d_in[7];
    const float* W3  = (const float*)d_in[8];  const float* b3  = (const float*)d_in[9];
    const float* Wmu = (const float*)d_in[10]; const float* bmu = (const float*)d_in[11];
    const float* Wlv = (const float*)d_in[12]; const float* blv = (const float*)d_in[13];
    const float* fc1w = (const float*)d_in[14]; const float* fc1b = (const float*)d_in[15];
    const float* fc2w = (const float*)d_in[16]; const float* fc2b = (const float*)d_in[17];

    const int* e_row = ei;
    const int* e_col = ei + E;

    float* out  = (float*)d_out;
    float* amvo = out;
    float* mu   = out + (size_t)N * F4;
    float* lv   = out + 2 * (size_t)N * F4;
    float* pmvo = out + 3 * (size_t)N * F4;

    // --- workspace carve ---
    char* w = (char*)d_ws;
    auto alloc = [&](size_t bytes) -> void* {
        void* p = (void*)w;
        w += (bytes + 255) & ~(size_t)255;
        return p;
    };
    float* dinv    = (float*)alloc((size_t)N * 4);
    int*   counts  = (int*)alloc((size_t)N * 4);
    int*   offsets = (int*)alloc((size_t)(N + 1) * 4);
    int*   csr_row = (int*)alloc((size_t)M * 4);
    float* csr_nrm = (float*)alloc((size_t)M * 4);
    int*   gstart  = (int*)alloc((size_t)(B + 1) * 4);
    unsigned short* xb  = (unsigned short*)alloc((size_t)N * F0 * 2);
    unsigned short* h1  = (unsigned short*)alloc((size_t)N * 128 * 2);
    unsigned short* h2  = (unsigned short*)alloc((size_t)N * 192 * 2);
    unsigned short* h3  = (unsigned short*)alloc((size_t)N * 256 * 2);
    unsigned short* g   = (unsigned short*)alloc((size_t)N * 256 * 2);  // reused g1..g4
    unsigned short* wt1 = (unsigned short*)alloc((size_t)64 * 128 * 2);
    unsigned short* wt2 = (unsigned short*)alloc((size_t)128 * 192 * 2);
    unsigned short* wt3 = (unsigned short*)alloc((size_t)192 * 256 * 2);
    unsigned short* wtm = (unsigned short*)alloc((size_t)256 * 256 * 2);
    unsigned short* wtl = (unsigned short*)alloc((size_t)256 * 256 * 2);
    float* x2  = (float*)alloc((size_t)B * F4 * 4);
    float* hid = (float*)alloc((size_t)B * 1024 * 4);
    (void)ws_size; (void)n_in;

    // --- 1. graph structure ---
    hipMemsetAsync(counts, 0, (size_t)N * 4, stream);
    k_count<<<ceil_div(E, THREADS), THREADS, 0, stream>>>(e_col, counts, E);
    k_dinv<<<ceil_div(N, THREADS), THREADS, 0, stream>>>(counts, dinv, N);
    k_scan<<<1, 1024, 0, stream>>>(counts, offsets, N);
    k_init_cursor<<<ceil_div(N, THREADS), THREADS, 0, stream>>>(offsets, counts, N);
    k_scatter<<<ceil_div(E + N, THREADS), THREADS, 0, stream>>>(
        e_row, e_col, dinv, counts, csr_row, csr_nrm, E, N);

    // --- 2. casts + weight prep ---
    k_cast_bf16<<<ceil_div(N * F0, THREADS), THREADS, 0, stream>>>(x, xb, N * F0);
    k_prep_w<<<ceil_div(64 * 128, THREADS), THREADS, 0, stream>>>(W1, wt1, 64, 128);
    k_prep_w<<<ceil_div(128 * 192, THREADS), THREADS, 0, stream>>>(W2, wt2, 128, 192);
    k_prep_w<<<ceil_div(192 * 256, THREADS), THREADS, 0, stream>>>(W3, wt3, 192, 256);
    k_prep_w<<<ceil_div(256 * 256, THREADS), THREADS, 0, stream>>>(Wmu, wtm, 256, 256);
    k_prep_w<<<ceil_div(256 * 256, THREADS), THREADS, 0, stream>>>(Wlv, wtl, 256, 256);

    const int nbm = ceil_div(N, GBM);          // 782
    const int nbm8 = ceil_div(nbm, 8) * 8;     // 784

    // --- 3. GCN stack: agg -> transform ---
    // g1 = agg(xb) [N,64]; h1 = relu(g1@W1+b1) [N,128]
    {
        dim3 blk(8, 32); // 64ch
        k_agg<<<ceil_div(N, 32), blk, 0, stream>>>(xb, offsets, csr_row, csr_nrm, g, N, 64);
        k_gemm_mfma<<<nbm8 * 2, 512, 0, stream>>>(g, wt1, b1, h1, N, 64, 128, 1, 1);
    }
    // g2 = agg(h1) [N,128]; h2 = relu(g2@W2+b2) [N,192]
    {
        dim3 blk(16, 16);
        k_agg<<<ceil_div(N, 16), blk, 0, stream>>>(h1, offsets, csr_row, csr_nrm, g, N, 128);
        k_gemm_mfma<<<nbm8 * 3, 512, 0, stream>>>(g, wt2, b2, h2, N, 128, 192, 1, 1);
    }
    // g3 = agg(h2) [N,192]; h3 = relu(g3@W3+b3) [N,256]
    {
        dim3 blk(24, 8);
        k_agg<<<ceil_div(N, 8), blk, 0, stream>>>(h2, offsets, csr_row, csr_nrm, g, N, 192);
        k_gemm_mfma<<<nbm8 * 4, 512, 0, stream>>>(g, wt3, b3, h3, N, 192, 256, 1, 1);
    }
    // g4 = agg(h3) [N,256]; fused: mu, lv, amvo in one pass
    {
        dim3 blk(32, 8);
        k_agg<<<ceil_div(N, 8), blk, 0, stream>>>(h3, offsets, csr_row, csr_nrm, g, N, 256);
        k_gemm_mfma_dual<<<nbm8 * 4, 512, 0, stream>>>(g, wtm, wtl, bmu, blv, eps,
                                                       mu, lv, amvo, N, 256, 256);
    }

    // --- 4. pool + MLP (fp32) ---
    k_gstart<<<ceil_div(B + 1, THREADS), THREADS, 0, stream>>>(batch, gstart, N, B);
    {
        dim3 gg(B, F4 / 64);
        dim3 blk(64, 4);
        k_pool_max<<<gg, blk, 0, stream>>>(h3, gstart, x2, F4);
    }
    k_fc1<<<B, 256, 0, stream>>>(x2, fc1w, fc1b, hid, F4, 1024);
    k_fc2<<<B, 128, 0, stream>>>(hid, fc2w, fc2b, pmvo, 1024, 128);
}